// Round 1
// baseline (3129.086 us; speedup 1.0000x reference)
//
#include <hip/hip_runtime.h>
#include <stdint.h>
#include <stddef.h>

#define NEXP 8
#define BTOK 8192
#define FDIM 2048
#define HDIM 8192
#define ODIM 2048
#define SLOT_CAP (2*BTOK + NEXP*128)   // 17408 max padded slots
#define MAX_TILES ((SLOT_CAP)/128)     // 136

typedef unsigned short u16;
typedef __attribute__((ext_vector_type(8))) short short8;   // 8 bf16 = 4 VGPRs
typedef __attribute__((ext_vector_type(4))) float f32x4;
typedef __attribute__((ext_vector_type(4))) unsigned int u32x4;

__device__ __forceinline__ u16 f2bf(float f) {
  union { float f; unsigned u; } v; v.f = f;
  unsigned r = v.u + 0x7fffu + ((v.u >> 16) & 1u);
  return (u16)(r >> 16);
}
__device__ __forceinline__ float bf2f(u16 h) {
  union { unsigned u; float f; } v; v.u = ((unsigned)h) << 16;
  return v.f;
}
__device__ __forceinline__ void async16(const void* g, void* l) {
  __builtin_amdgcn_global_load_lds(
      (const __attribute__((address_space(1))) unsigned int*)g,
      (__attribute__((address_space(3))) unsigned int*)l, 16, 0, 0);
}

// ---------------- router: scores -> top2 -> softmax weights ----------------
__global__ __launch_bounds__(256) void router_k(
    const float* __restrict__ X, const float* __restrict__ gW,
    const float* __restrict__ gb, const float* __restrict__ eb,
    int* __restrict__ tok_e, float* __restrict__ tok_w, int* __restrict__ cnt)
{
  const int wave = threadIdx.x >> 6, lane = threadIdx.x & 63;
  const int t = blockIdx.x * 4 + wave;
  const float* xr = X + (size_t)t * FDIM;
  float acc[8];
#pragma unroll
  for (int e = 0; e < 8; ++e) acc[e] = 0.f;
  for (int i = 0; i < FDIM / 64; ++i) {
    const int f = i * 64 + lane;
    const float x = xr[f];
    const float4* gp = (const float4*)(gW + (size_t)f * 8);
    float4 g0 = gp[0], g1 = gp[1];
    acc[0] += x * g0.x; acc[1] += x * g0.y; acc[2] += x * g0.z; acc[3] += x * g0.w;
    acc[4] += x * g1.x; acc[5] += x * g1.y; acc[6] += x * g1.z; acc[7] += x * g1.w;
  }
#pragma unroll
  for (int off = 32; off > 0; off >>= 1) {
#pragma unroll
    for (int e = 0; e < 8; ++e) acc[e] += __shfl_down(acc[e], off, 64);
  }
  if (lane == 0) {
    float s[8];
#pragma unroll
    for (int e = 0; e < 8; ++e) s[e] = acc[e] + gb[e] + eb[e];
    int bi = 0; float bv = s[0];
    for (int e = 1; e < 8; ++e) if (s[e] > bv) { bv = s[e]; bi = e; }
    int si = -1; float sv = -3.4e38f;
    for (int e = 0; e < 8; ++e) if (e != bi && s[e] > sv) { sv = s[e]; si = e; }
    float r = expf(sv - bv);          // <= 1
    float w0 = 1.f / (1.f + r);
    tok_e[2 * t] = bi; tok_e[2 * t + 1] = si;
    tok_w[2 * t] = w0; tok_w[2 * t + 1] = 1.f - w0;
    atomicAdd(&cnt[bi], 1); atomicAdd(&cnt[si], 1);
  }
}

// ------------- scan counts -> padded segment offsets, init slots -----------
__global__ void scan_init_k(const int* __restrict__ cnt, int* __restrict__ cursor,
                            int* __restrict__ total, int* __restrict__ slot_tok,
                            int* __restrict__ expert_of)
{
  __shared__ int soff[9];
  if (threadIdx.x == 0) {
    int acc = 0;
    for (int e = 0; e < 8; ++e) {
      soff[e] = acc; cursor[e] = acc;
      acc += ((cnt[e] + 127) >> 7) << 7;   // pad each segment to x128
    }
    soff[8] = acc; *total = acc;
  }
  __syncthreads();
  const int tp = soff[8];
  for (int s = threadIdx.x; s < tp; s += 256) {
    slot_tok[s] = -1;
    int e = 0;
    while (e < 7 && s >= soff[e + 1]) ++e;
    expert_of[s] = e;
  }
}

__global__ void fill_k(const int* __restrict__ tok_e, int* __restrict__ cursor,
                       int* __restrict__ slot_tok, int* __restrict__ slot_of)
{
  int t = blockIdx.x * 256 + threadIdx.x;
  if (t >= BTOK) return;
#pragma unroll
  for (int k = 0; k < 2; ++k) {
    int e = tok_e[2 * t + k];
    int pos = atomicAdd(&cursor[e], 1);
    slot_tok[pos] = t;
    slot_of[2 * t + k] = pos;
  }
}

// ---------------- X fp32 -> bf16 ----------------
__global__ __launch_bounds__(256) void xcvt_k(const float* __restrict__ X, u16* __restrict__ Xb) {
  const size_t i = ((size_t)blockIdx.x * 256 + threadIdx.x) * 4;
  float4 v = *(const float4*)(X + i);
  union { u16 s[4]; unsigned long long u; } pk;
  pk.s[0] = f2bf(v.x); pk.s[1] = f2bf(v.y); pk.s[2] = f2bf(v.z); pk.s[3] = f2bf(v.w);
  *(unsigned long long*)(Xb + i) = pk.u;
}

// --------- W [E][M][N] fp32 -> Wt [E][N][M] bf16 (transpose+convert) -------
__global__ __launch_bounds__(256) void tcvt_k(const float* __restrict__ src,
                                              u16* __restrict__ dst, int M, int N)
{
  const int e = blockIdx.z;
  src += (size_t)e * M * N;
  dst += (size_t)e * M * N;
  const int c0 = blockIdx.x * 64;   // along N
  const int r0 = blockIdx.y * 64;   // along M
  __shared__ u16 tile[64][65];
  const int tid = threadIdx.x;
  const int rr = tid >> 4, cc = (tid & 15) * 4;
#pragma unroll
  for (int i = 0; i < 4; ++i) {
    const int r = rr + i * 16;
    float4 v = *(const float4*)(src + (size_t)(r0 + r) * N + c0 + cc);
    tile[r][cc + 0] = f2bf(v.x); tile[r][cc + 1] = f2bf(v.y);
    tile[r][cc + 2] = f2bf(v.z); tile[r][cc + 3] = f2bf(v.w);
  }
  __syncthreads();
  const int hr = tid >> 2, fc = (tid & 3) * 16;
  union { u16 s[16]; u32x4 v[2]; } buf;
#pragma unroll
  for (int j = 0; j < 16; ++j) buf.s[j] = tile[fc + j][hr];
  u16* o = dst + (size_t)(c0 + hr) * M + r0 + fc;
  *(u32x4*)o = buf.v[0];
  *(u32x4*)(o + 8) = buf.v[1];
}

// ---------------- grouped GEMM: C[slot][n] = A(row(slot)) @ Bt[e][n][:] ----
// 128x128 tile, BK=64, 4 waves, 4x4 frags of mfma_f32_16x16x32_bf16.
// LDS A/B packed [128][64] bf16 with XOR chunk swizzle (global_load_lds-safe).
template<int KDIM, int NDIM, bool GATHER, bool RELU, bool BIAS>
__global__ __launch_bounds__(256) void gemm_moe(
    const u16* __restrict__ Abase, const u16* __restrict__ Bt,
    const float* __restrict__ bias, const int* __restrict__ slot_tok,
    const int* __restrict__ expert_of, const int* __restrict__ total_ptr,
    u16* __restrict__ Cout)
{
  __shared__ __align__(16) u16 smem[17408];   // A:[0,8192) B:[8192,16384) ushorts; C reuse: 128x136
  const int tile_m = blockIdx.x, tile_n = blockIdx.y;
  const int total = *total_ptr;
  const int m0 = tile_m * 128;
  if (m0 >= total) return;
  const int e = expert_of[m0];

  const int tid = threadIdx.x;
  const int lane = tid & 63, w = tid >> 6;
  const int wm = w & 1, wn = w >> 1;

  // staging pointers: instr i covers rows w*32+i*8 .. +7; lane -> (row=l/8, chunk=l%8)
  const u16* ga[4]; const u16* gbp[4];
  u16* la[4]; u16* lb[4];
#pragma unroll
  for (int i = 0; i < 4; ++i) {
    const int rl = w * 32 + i * 8 + (lane >> 3);
    const int cg = (lane & 7) ^ (rl & 7);        // XOR swizzle on global chunk
    int arow;
    if (GATHER) { int tk = slot_tok[m0 + rl]; arow = tk < 0 ? 0 : tk; }
    else arow = m0 + rl;
    ga[i]  = Abase + (size_t)arow * KDIM + cg * 8;
    gbp[i] = Bt + ((size_t)e * NDIM + (size_t)(tile_n * 128 + rl)) * KDIM + cg * 8;
    la[i] = &smem[(w * 32 + i * 8) * 64];
    lb[i] = &smem[8192 + (w * 32 + i * 8) * 64];
  }

  const int quad = lane >> 4;
  const int l15 = lane & 15;
  const int co0 = ((quad) ^ (lane & 7)) * 8;       // k-chunk lds offset, kk=0
  const int co1 = ((4 + quad) ^ (lane & 7)) * 8;   // kk=1

  f32x4 zero = {0.f, 0.f, 0.f, 0.f};
  f32x4 acc[4][4];
#pragma unroll
  for (int mt = 0; mt < 4; ++mt)
#pragma unroll
    for (int nt = 0; nt < 4; ++nt) acc[mt][nt] = zero;

  for (int kb = 0; kb < KDIM / 64; ++kb) {
#pragma unroll
    for (int i = 0; i < 4; ++i) async16(ga[i], la[i]);
#pragma unroll
    for (int i = 0; i < 4; ++i) async16(gbp[i], lb[i]);
    __syncthreads();
#pragma unroll
    for (int kk = 0; kk < 2; ++kk) {
      const int co = kk ? co1 : co0;
      short8 af[4], bfr[4];
#pragma unroll
      for (int mt = 0; mt < 4; ++mt)
        af[mt] = *(const short8*)&smem[(wm * 64 + mt * 16 + l15) * 64 + co];
#pragma unroll
      for (int nt = 0; nt < 4; ++nt)
        bfr[nt] = *(const short8*)&smem[8192 + (wn * 64 + nt * 16 + l15) * 64 + co];
#pragma unroll
      for (int mt = 0; mt < 4; ++mt)
#pragma unroll
        for (int nt = 0; nt < 4; ++nt)
          acc[mt][nt] = __builtin_amdgcn_mfma_f32_16x16x32_bf16(af[mt], bfr[nt], acc[mt][nt], 0, 0, 0);
    }
    __syncthreads();
#pragma unroll
    for (int i = 0; i < 4; ++i) { ga[i] += 64; gbp[i] += 64; }
  }

  // epilogue: bias+relu, C frags -> LDS [128][136] bf16, then coalesced store
  float bv[4];
  if (BIAS) {
#pragma unroll
    for (int nt = 0; nt < 4; ++nt)
      bv[nt] = bias[(size_t)e * NDIM + tile_n * 128 + wn * 64 + nt * 16 + l15];
  }
#pragma unroll
  for (int mt = 0; mt < 4; ++mt)
#pragma unroll
    for (int nt = 0; nt < 4; ++nt) {
      const int col = wn * 64 + nt * 16 + l15;
#pragma unroll
      for (int j = 0; j < 4; ++j) {
        const int row = wm * 64 + mt * 16 + quad * 4 + j;
        float v = acc[mt][nt][j];
        if (BIAS) v += bv[nt];
        if (RELU) v = fmaxf(v, 0.f);
        smem[row * 136 + col] = f2bf(v);
      }
    }
  __syncthreads();
  {
    const int r = tid >> 1, half = tid & 1;
    const size_t orow = (size_t)(m0 + r) * NDIM + (size_t)tile_n * 128 + half * 64;
    const int base = r * 136 + half * 64;
#pragma unroll
    for (int t2 = 0; t2 < 8; ++t2) {
      u32x4 v = *(const u32x4*)&smem[base + t2 * 8];
      *(u32x4*)&Cout[orow + t2 * 8] = v;
    }
  }
}

// ---------------- combine: out[t] = w0*(y[s0]+b2[e0]) + w1*(y[s1]+b2[e1]) ----
__global__ __launch_bounds__(256) void combine_k(
    const u16* __restrict__ ybuf, const int* __restrict__ slot_of,
    const int* __restrict__ tok_e, const float* __restrict__ tok_w,
    const float* __restrict__ b2, float* __restrict__ out)
{
  const int idx = blockIdx.x * 256 + threadIdx.x;
  const int t = idx >> 9;            // 512 float4 per token row
  const int o = (idx & 511) * 4;
  const int s0 = slot_of[2 * t], s1 = slot_of[2 * t + 1];
  const float w0 = tok_w[2 * t], w1 = tok_w[2 * t + 1];
  const int e0 = tok_e[2 * t], e1 = tok_e[2 * t + 1];
  union { u16 s[4]; unsigned long long u; } y0, y1;
  y0.u = *(const unsigned long long*)(ybuf + (size_t)s0 * ODIM + o);
  y1.u = *(const unsigned long long*)(ybuf + (size_t)s1 * ODIM + o);
  float4 bb0 = *(const float4*)(b2 + (size_t)e0 * ODIM + o);
  float4 bb1 = *(const float4*)(b2 + (size_t)e1 * ODIM + o);
  float4 r;
  r.x = w0 * (bf2f(y0.s[0]) + bb0.x) + w1 * (bf2f(y1.s[0]) + bb1.x);
  r.y = w0 * (bf2f(y0.s[1]) + bb0.y) + w1 * (bf2f(y1.s[1]) + bb1.y);
  r.z = w0 * (bf2f(y0.s[2]) + bb0.z) + w1 * (bf2f(y1.s[2]) + bb1.z);
  r.w = w0 * (bf2f(y0.s[3]) + bb0.w) + w1 * (bf2f(y1.s[3]) + bb1.w);
  *(float4*)(out + (size_t)t * ODIM + o) = r;
}

__global__ void sentinel_k(float* out) {
  size_t i = (size_t)blockIdx.x * 256 + threadIdx.x;
  out[i] = 1.0e9f;   // unambiguous "workspace too small" marker
}

// ---------------- workspace layout (bytes) ----------------
#define W1T_OFF   ((size_t)0)
#define W2T_OFF   ((size_t)268435456)
#define XB_OFF    ((size_t)536870912)
#define HBUF_OFF  ((size_t)570425344)
#define YBUF_OFF  ((size_t)855638016)
#define META_OFF  ((size_t)926941184)
// meta sublayout
#define M_CNT     0
#define M_CURSOR  64
#define M_TOTAL   128
#define M_TOKE    256
#define M_TOKW    (256 + 65536)
#define M_SLOTOF  (256 + 2*65536)
#define M_SLOTTOK (256 + 3*65536)
#define M_EXPOF   (256 + 3*65536 + 69632)
#define WS_NEEDED (META_OFF + (size_t)(256 + 3*65536 + 2*69632))

extern "C" void kernel_launch(void* const* d_in, const int* in_sizes, int n_in,
                              void* d_out, int out_size, void* d_ws, size_t ws_size,
                              hipStream_t stream) {
  const float* X  = (const float*)d_in[0];
  const float* gW = (const float*)d_in[1];
  const float* gb = (const float*)d_in[2];
  const float* eb = (const float*)d_in[3];
  const float* W1 = (const float*)d_in[4];
  const float* b1 = (const float*)d_in[5];
  const float* W2 = (const float*)d_in[6];
  const float* b2 = (const float*)d_in[7];
  float* out = (float*)d_out;
  char* ws = (char*)d_ws;

  if (ws_size < WS_NEEDED) {          // signal: absmax will read ~1e9
    sentinel_k<<<65536, 256, 0, stream>>>(out);
    return;
  }

  u16* W1t = (u16*)(ws + W1T_OFF);
  u16* W2t = (u16*)(ws + W2T_OFF);
  u16* Xb  = (u16*)(ws + XB_OFF);
  u16* hbuf = (u16*)(ws + HBUF_OFF);
  u16* ybuf = (u16*)(ws + YBUF_OFF);
  char* meta = ws + META_OFF;
  int* cnt      = (int*)(meta + M_CNT);
  int* cursor   = (int*)(meta + M_CURSOR);
  int* total    = (int*)(meta + M_TOTAL);
  int* tok_e    = (int*)(meta + M_TOKE);
  float* tok_w  = (float*)(meta + M_TOKW);
  int* slot_of  = (int*)(meta + M_SLOTOF);
  int* slot_tok = (int*)(meta + M_SLOTTOK);
  int* expert_of= (int*)(meta + M_EXPOF);

  hipMemsetAsync(meta, 0, 192, stream);   // cnt + cursor + total

  router_k<<<BTOK / 4, 256, 0, stream>>>(X, gW, gb, eb, tok_e, tok_w, cnt);
  scan_init_k<<<1, 256, 0, stream>>>(cnt, cursor, total, slot_tok, expert_of);
  fill_k<<<BTOK / 256, 256, 0, stream>>>(tok_e, cursor, slot_tok, slot_of);

  xcvt_k<<<(BTOK * FDIM) / (256 * 4), 256, 0, stream>>>(X, Xb);
  tcvt_k<<<dim3(HDIM / 64, FDIM / 64, NEXP), 256, 0, stream>>>(W1, W1t, FDIM, HDIM);
  tcvt_k<<<dim3(ODIM / 64, HDIM / 64, NEXP), 256, 0, stream>>>(W2, W2t, HDIM, ODIM);

  gemm_moe<FDIM, HDIM, true,  true,  true ><<<dim3(MAX_TILES, HDIM / 128), 256, 0, stream>>>(
      Xb, W1t, b1, slot_tok, expert_of, total, hbuf);
  gemm_moe<HDIM, ODIM, false, false, false><<<dim3(MAX_TILES, ODIM / 128), 256, 0, stream>>>(
      hbuf, W2t, nullptr, nullptr, expert_of, total, ybuf);

  combine_k<<<(BTOK * ODIM) / (256 * 4), 256, 0, stream>>>(ybuf, slot_of, tok_e, tok_w, b2, out);
}